// Round 4
// baseline (4382.191 us; speedup 1.0000x reference)
//
#include <hip/hip_runtime.h>
#include <cmath>

#ifndef M_PI
#define M_PI 3.14159265358979323846
#endif

static constexpr int CH     = 128;   // channels
static constexpr int NBATCH = 64;    // batch
static constexpr int HWSZ   = 3136;  // 56*56
static constexpr int HW4    = 784;   // HWSZ/4
static constexpr int PARTS  = 16;    // chunks per channel in main sweep
static constexpr int SLPP   = NBATCH / PARTS;
static constexpr int KTOP   = 10;
static constexpr float EPSV = 1e-5f;
static constexpr int LBUF   = 4096;  // per-block LDS candidate buffer (floats)
static constexpr int SELMAX = 4096;  // finalize fast-path LDS capacity

// ---------------------------------------------------------------------------
// k_sample: per channel, strided 784-float4 sample -> mu_hat, tau_pre.
// Also zeroes cnt/ovf.  grid = CH blocks, 256 threads.
// ---------------------------------------------------------------------------
__global__ __launch_bounds__(256) void k_sample(const float* __restrict__ x,
                                                float* __restrict__ muhat,
                                                float* __restrict__ taupre,
                                                unsigned* __restrict__ cnt,
                                                unsigned* __restrict__ ovf) {
  const int c   = blockIdx.x;
  const int tid = threadIdx.x;
  const float4* x4 = reinterpret_cast<const float4*>(x);
  const int lane = tid & 63, wid = tid >> 6;
  __shared__ float shA[4], shB[4];

  float s = 0.f;
  for (int j = tid; j < HW4; j += 256) {
    const int n = j & 63;   // spread samples across all 64 batch slices
    float4 v = x4[(size_t)(n * CH + c) * HW4 + j];
    s += (v.x + v.y) + (v.z + v.w);
  }
  for (int off = 32; off; off >>= 1) s += __shfl_down(s, off);
  if (lane == 0) shA[wid] = s;
  __syncthreads();
  const float mu = ((shA[0] + shA[1]) + (shA[2] + shA[3])) * (1.0f / (4.0f * HW4));

  float m = 0.f;
  for (int j = tid; j < HW4; j += 256) {
    const int n = j & 63;
    float4 v = x4[(size_t)(n * CH + c) * HW4 + j];  // L2-hot re-read
    m = fmaxf(m, fmaxf(fmaxf(fabsf(v.x - mu), fabsf(v.y - mu)),
                       fmaxf(fabsf(v.z - mu), fabsf(v.w - mu))));
  }
  for (int off = 32; off; off >>= 1) m = fmaxf(m, __shfl_down(m, off));
  if (lane == 0) shB[wid] = m;
  __syncthreads();
  if (tid == 0) {
    const float mm = fmaxf(fmaxf(shB[0], shB[1]), fmaxf(shB[2], shB[3]));
    muhat[c]  = mu;
    taupre[c] = 0.88f * mm;   // ~3.0 sigma: >>10 candidates, far below d10
    cnt[c]    = 0u;
    ovf[c]    = 0u;
  }
}

// ---------------------------------------------------------------------------
// k_main: ONE sweep of x: exact partial sums + candidate collection
// (raw values v with |v - mu_hat| >= tau_pre), LDS-buffered, 1 global
// atomic per block.  grid = PARTS*CH = 2048 blocks, 256 threads.
// ---------------------------------------------------------------------------
__global__ __launch_bounds__(256) void k_main(const float* __restrict__ x,
                                              const float* __restrict__ muhat,
                                              const float* __restrict__ taupre,
                                              float* __restrict__ sums,
                                              unsigned* __restrict__ cnt,
                                              unsigned* __restrict__ ovf,
                                              float* __restrict__ cand,
                                              int cap) {
  __shared__ float buf[LBUF];
  __shared__ unsigned lcnt;
  __shared__ unsigned gbase;
  __shared__ float shs[4];
  const int bid  = blockIdx.x;
  const int c    = bid & (CH - 1);
  const int part = bid >> 7;
  const int tid  = threadIdx.x;
  if (tid == 0) lcnt = 0u;
  __syncthreads();

  const float mu = muhat[c], t = taupre[c];
  const float4* x4 = reinterpret_cast<const float4*>(x);

  float s = 0.f;
  for (int sl = 0; sl < SLPP; ++sl) {
    const size_t base = (size_t)((part * SLPP + sl) * CH + c) * HW4;
    for (int i = tid; i < HW4; i += 256) {
      float4 v = x4[base + i];
      s += (v.x + v.y) + (v.z + v.w);
      if (fabsf(v.x - mu) >= t) { unsigned p = atomicAdd(&lcnt, 1u); if (p < LBUF) buf[p] = v.x; }
      if (fabsf(v.y - mu) >= t) { unsigned p = atomicAdd(&lcnt, 1u); if (p < LBUF) buf[p] = v.y; }
      if (fabsf(v.z - mu) >= t) { unsigned p = atomicAdd(&lcnt, 1u); if (p < LBUF) buf[p] = v.z; }
      if (fabsf(v.w - mu) >= t) { unsigned p = atomicAdd(&lcnt, 1u); if (p < LBUF) buf[p] = v.w; }
    }
  }
  for (int off = 32; off; off >>= 1) s += __shfl_down(s, off);
  const int lane = tid & 63, wid = tid >> 6;
  if (lane == 0) shs[wid] = s;
  __syncthreads();   // also guarantees all LDS-atomic pushes are complete

  if (tid == 0) {
    sums[bid] = (shs[0] + shs[1]) + (shs[2] + shs[3]);
    gbase = atomicAdd(&cnt[c], lcnt);   // true attempted count
    if (lcnt > LBUF) ovf[c] = 1u;
  }
  __syncthreads();

  const unsigned n  = min(lcnt, (unsigned)LBUF);
  const unsigned gb = gbase;
  float* cc = cand + (size_t)c * cap;
  for (unsigned i = tid; i < n; i += 256) {
    const unsigned p = gb + i;
    if (p < (unsigned)cap) cc[p] = buf[i];
  }
}

// ---------------------------------------------------------------------------
// k_finalize: per channel: exact mean, exact top-10 of |v-mu| over
// candidates (fast path, LDS) or full stream (fallback), fold (sw, sb).
// grid = CH blocks, 256 threads.
// ---------------------------------------------------------------------------
__global__ __launch_bounds__(256) void k_finalize(const float* __restrict__ sums,
                                                  const unsigned* __restrict__ cnt,
                                                  const unsigned* __restrict__ ovf,
                                                  const float* __restrict__ cand,
                                                  const float* __restrict__ x,
                                                  const float* __restrict__ weight,
                                                  const float* __restrict__ bias,
                                                  float* __restrict__ sw,
                                                  float* __restrict__ sb,
                                                  int cap, float constv) {
  const int c   = blockIdx.x;
  const int tid = threadIdx.x;
  const int lane = tid & 63, wid = tid >> 6;

  // exact mean from 16 partials (wave 0 does the reduce)
  __shared__ float smu;
  float ps = (tid < PARTS) ? sums[tid * CH + c] : 0.f;
  for (int off = 32; off; off >>= 1) ps += __shfl_down(ps, off);
  if (tid == 0) smu = ps * (1.0f / ((float)NBATCH * (float)HWSZ));
  __syncthreads();
  const float mu = smu;

  const unsigned n = cnt[c];
  const unsigned capu = (unsigned)cap;
  const bool good = (n >= (unsigned)KTOP) && (n <= capu) &&
                    (n <= (unsigned)SELMAX) && (ovf[c] == 0u);

  __shared__ float swv[4];
  __shared__ int   swi[4];
  __shared__ float tot;
  if (tid == 0) tot = 0.f;
  __syncthreads();

  if (good) {
    __shared__ float ls[SELMAX];
    const float* cc = cand + (size_t)c * cap;
    for (unsigned i = tid; i < n; i += 256) ls[i] = fabsf(cc[i] - mu);
    __syncthreads();
    for (int it = 0; it < KTOP; ++it) {
      float best = -1.f; int bi = 0;
      for (unsigned i = tid; i < n; i += 256) {
        float v = ls[i];
        if (v > best) { best = v; bi = (int)i; }
      }
      for (int off = 32; off; off >>= 1) {
        float ov = __shfl_down(best, off);
        int   oi = __shfl_down(bi, off);
        if (ov > best) { best = ov; bi = oi; }
      }
      if (lane == 0) { swv[wid] = best; swi[wid] = bi; }
      __syncthreads();
      if (tid == 0) {
        float bb = swv[0]; int bbi = swi[0];
        for (int w = 1; w < 4; ++w) if (swv[w] > bb) { bb = swv[w]; bbi = swi[w]; }
        tot += bb;
        ls[bbi] = -1.f;
      }
      __syncthreads();
    }
  } else {
    // exact fallback: stream the whole channel, exclude chosen by index
    __shared__ int chosen[KTOP];
    for (int it = 0; it < KTOP; ++it) {
      float best = -1.f; int bi = -1;
      for (int j = tid; j < NBATCH * HWSZ; j += 256) {
        bool skip = false;
        for (int q = 0; q < it; ++q) skip = skip || (chosen[q] == j);
        if (skip) continue;
        const int nn = j / HWSZ, pos = j - nn * HWSZ;
        const float v = x[(size_t)(nn * CH + c) * HWSZ + pos];
        const float d = fabsf(v - mu);
        if (d > best) { best = d; bi = j; }
      }
      for (int off = 32; off; off >>= 1) {
        float ov = __shfl_down(best, off);
        int   oi = __shfl_down(bi, off);
        if (ov > best) { best = ov; bi = oi; }
      }
      if (lane == 0) { swv[wid] = best; swi[wid] = bi; }
      __syncthreads();
      if (tid == 0) {
        float bb = swv[0]; int bbi = swi[0];
        for (int w = 1; w < 4; ++w) if (swv[w] > bb) { bb = swv[w]; bbi = swi[w]; }
        tot += bb;
        chosen[it] = bbi;
      }
      __syncthreads();
    }
  }

  if (tid == 0) {
    const float mtk = tot * (1.0f / KTOP) * constv;
    const float inv = 1.f / (mtk + EPSV);
    const float w   = inv * weight[c];
    sw[c] = w;
    sb[c] = bias[c] - mu * w;
  }
}

// ---------------------------------------------------------------------------
// k_affine: out = fma(x, sw[c], sb[c]).  grid = NBATCH*CH, 256 threads
// ---------------------------------------------------------------------------
__global__ __launch_bounds__(256) void k_affine(const float* __restrict__ x,
                                                const float* __restrict__ sw,
                                                const float* __restrict__ sb,
                                                float* __restrict__ out) {
  const int s = blockIdx.x;           // n*CH + c
  const int c = s & (CH - 1);
  const float w = sw[c], b = sb[c];
  const float4* x4 = reinterpret_cast<const float4*>(x) + (size_t)s * HW4;
  float4*       o4 = reinterpret_cast<float4*>(out)     + (size_t)s * HW4;
  for (int i = threadIdx.x; i < HW4; i += 256) {
    float4 v = x4[i];
    float4 r;
    r.x = fmaf(v.x, w, b);
    r.y = fmaf(v.y, w, b);
    r.z = fmaf(v.z, w, b);
    r.w = fmaf(v.w, w, b);
    o4[i] = r;
  }
}

extern "C" void kernel_launch(void* const* d_in, const int* in_sizes, int n_in,
                              void* d_out, int out_size, void* d_ws, size_t ws_size,
                              hipStream_t stream) {
  const float* x      = (const float*)d_in[0];
  const float* weight = (const float*)d_in[1];
  const float* bias   = (const float*)d_in[2];
  float* out = (float*)d_out;
  float* ws  = (float*)d_ws;

  // ws layout (floats)
  float*    sums   = ws;                     // PARTS*CH = 2048
  float*    muhat  = sums + PARTS * CH;      // 128
  float*    taupre = muhat + CH;             // 128
  float*    sw     = taupre + CH;            // 128
  float*    sb     = sw + CH;                // 128
  unsigned* cnt    = (unsigned*)(sb + CH);   // 128
  unsigned* ovf    = cnt + CH;               // 128
  float*    cand   = (float*)(ovf + CH);
  const size_t FIXED = (size_t)((float*)cand - ws);

  const size_t avail = ws_size / 4;
  int cap;
  if      (avail >= FIXED + (size_t)CH * 8192) cap = 8192;
  else if (avail >= FIXED + (size_t)CH * 2048) cap = 2048;
  else                                         cap = 1024;

  const double M = (double)NBATCH * (double)HWSZ;
  const float constv =
      (float)(0.5 * (1.0 + sqrt(M_PI * log(4.0))) / sqrt(2.0 * log(M)));

  k_sample<<<CH, 256, 0, stream>>>(x, muhat, taupre, cnt, ovf);
  k_main<<<PARTS * CH, 256, 0, stream>>>(x, muhat, taupre, sums, cnt, ovf, cand, cap);
  k_finalize<<<CH, 256, 0, stream>>>(sums, cnt, ovf, cand, x, weight, bias,
                                     sw, sb, cap, constv);
  k_affine<<<NBATCH * CH, 256, 0, stream>>>(x, sw, sb, out);
}

// Round 5
// 109.015 us; speedup vs baseline: 40.1981x; 40.1981x over previous
//
#include <hip/hip_runtime.h>
#include <cmath>

#ifndef M_PI
#define M_PI 3.14159265358979323846
#endif

static constexpr int CH     = 128;   // channels
static constexpr int NBATCH = 64;    // batch
static constexpr int HWSZ   = 3136;  // 56*56
static constexpr int HW4    = 784;   // HWSZ/4
static constexpr int PARTS  = 16;    // chunks per channel in main sweep
static constexpr int SLPP   = NBATCH / PARTS;
static constexpr int KTOP   = 10;
static constexpr float EPSV = 1e-5f;
static constexpr int LBUF   = 4096;  // per-block LDS candidate buffer (floats)
static constexpr int SELMAX = 4096;  // finalize fast-path LDS capacity

// one-sided compare-swap (keep ascending: a<=b)
#define CSA(a,b) { float lo_=fminf(a,b), hi_=fmaxf(a,b); a=lo_; b=hi_; }

// ---------------------------------------------------------------------------
// k_sample: per channel, strided 784-float4 sample -> mu_hat, tau_pre.
// Also zeroes cnt/ovf.  grid = CH blocks, 256 threads.
// ---------------------------------------------------------------------------
__global__ __launch_bounds__(256) void k_sample(const float* __restrict__ x,
                                                float* __restrict__ muhat,
                                                float* __restrict__ taupre,
                                                unsigned* __restrict__ cnt,
                                                unsigned* __restrict__ ovf) {
  const int c   = blockIdx.x;
  const int tid = threadIdx.x;
  const float4* x4 = reinterpret_cast<const float4*>(x);
  const int lane = tid & 63, wid = tid >> 6;
  __shared__ float shA[4], shB[4];

  float s = 0.f;
  for (int j = tid; j < HW4; j += 256) {
    const int n = j & 63;   // spread samples across all 64 batch slices
    float4 v = x4[(size_t)(n * CH + c) * HW4 + j];
    s += (v.x + v.y) + (v.z + v.w);
  }
  for (int off = 32; off; off >>= 1) s += __shfl_down(s, off);
  if (lane == 0) shA[wid] = s;
  __syncthreads();
  const float mu = ((shA[0] + shA[1]) + (shA[2] + shA[3])) * (1.0f / (4.0f * HW4));

  float m = 0.f;
  for (int j = tid; j < HW4; j += 256) {
    const int n = j & 63;
    float4 v = x4[(size_t)(n * CH + c) * HW4 + j];  // L3-hot re-read
    m = fmaxf(m, fmaxf(fmaxf(fabsf(v.x - mu), fabsf(v.y - mu)),
                       fmaxf(fabsf(v.z - mu), fabsf(v.w - mu))));
  }
  for (int off = 32; off; off >>= 1) m = fmaxf(m, __shfl_down(m, off));
  if (lane == 0) shB[wid] = m;
  __syncthreads();
  if (tid == 0) {
    const float mm = fmaxf(fmaxf(shB[0], shB[1]), fmaxf(shB[2], shB[3]));
    muhat[c]  = mu;
    taupre[c] = 0.82f * mm;   // ~2.9 sigma: plenty of candidates, below d10
    cnt[c]    = 0u;
    ovf[c]    = 0u;
  }
}

// ---------------------------------------------------------------------------
// k_main: ONE sweep of x: exact partial sums + candidate collection
// (raw values v with |v - mu_hat| >= tau_pre), LDS-buffered, 1 global
// atomic per block.  grid = PARTS*CH = 2048 blocks, 256 threads.
// ---------------------------------------------------------------------------
__global__ __launch_bounds__(256) void k_main(const float* __restrict__ x,
                                              const float* __restrict__ muhat,
                                              const float* __restrict__ taupre,
                                              float* __restrict__ sums,
                                              unsigned* __restrict__ cnt,
                                              unsigned* __restrict__ ovf,
                                              float* __restrict__ cand,
                                              int cap) {
  __shared__ float buf[LBUF];
  __shared__ unsigned lcnt;
  __shared__ unsigned gbase;
  __shared__ float shs[4];
  const int bid  = blockIdx.x;
  const int c    = bid & (CH - 1);
  const int part = bid >> 7;
  const int tid  = threadIdx.x;
  if (tid == 0) lcnt = 0u;
  __syncthreads();

  const float mu = muhat[c], t = taupre[c];
  const float4* x4 = reinterpret_cast<const float4*>(x);

  float s = 0.f;
  for (int sl = 0; sl < SLPP; ++sl) {
    const size_t base = (size_t)((part * SLPP + sl) * CH + c) * HW4;
    for (int i = tid; i < HW4; i += 256) {
      float4 v = x4[base + i];
      s += (v.x + v.y) + (v.z + v.w);
      if (fabsf(v.x - mu) >= t) { unsigned p = atomicAdd(&lcnt, 1u); if (p < LBUF) buf[p] = v.x; }
      if (fabsf(v.y - mu) >= t) { unsigned p = atomicAdd(&lcnt, 1u); if (p < LBUF) buf[p] = v.y; }
      if (fabsf(v.z - mu) >= t) { unsigned p = atomicAdd(&lcnt, 1u); if (p < LBUF) buf[p] = v.z; }
      if (fabsf(v.w - mu) >= t) { unsigned p = atomicAdd(&lcnt, 1u); if (p < LBUF) buf[p] = v.w; }
    }
  }
  for (int off = 32; off; off >>= 1) s += __shfl_down(s, off);
  const int lane = tid & 63, wid = tid >> 6;
  if (lane == 0) shs[wid] = s;
  __syncthreads();   // also guarantees all LDS-atomic pushes are complete

  if (tid == 0) {
    sums[bid] = (shs[0] + shs[1]) + (shs[2] + shs[3]);
    gbase = atomicAdd(&cnt[c], lcnt);   // true attempted count
    if (lcnt > LBUF) ovf[c] = 1u;
  }
  __syncthreads();

  const unsigned n  = min(lcnt, (unsigned)LBUF);
  const unsigned gb = gbase;
  float* cc = cand + (size_t)c * cap;
  for (unsigned i = tid; i < n; i += 256) {
    const unsigned p = gb + i;
    if (p < (unsigned)cap) cc[p] = buf[i];
  }
}

// ---------------------------------------------------------------------------
// k_rescue: parallel exact per-part top-10 for BAD channels only.
// grid = PARTS*CH, 256 threads. Good-channel blocks exit immediately.
// ---------------------------------------------------------------------------
__global__ __launch_bounds__(256) void k_rescue(const float* __restrict__ x,
                                                const float* __restrict__ sums,
                                                const unsigned* __restrict__ cnt,
                                                const unsigned* __restrict__ ovf,
                                                float* __restrict__ tops,
                                                int cap) {
  const int bid  = blockIdx.x;
  const int c    = bid & (CH - 1);
  const int part = bid >> 7;
  const int tid  = threadIdx.x;

  const unsigned n = cnt[c];
  const bool bad = (n < (unsigned)KTOP) || (n > (unsigned)cap) ||
                   (n > (unsigned)SELMAX) || (ovf[c] != 0u);
  if (!bad) return;

  // exact mu from 16 partial sums (every thread computes it redundantly)
  float mu = 0.f;
  #pragma unroll
  for (int p = 0; p < PARTS; ++p) mu += sums[p * CH + c];
  mu *= (1.0f / ((float)NBATCH * (float)HWSZ));

  // per-thread top-10 of dev (one-sided insert chain)
  float t0=-1.f,t1=-1.f,t2=-1.f,t3=-1.f,t4=-1.f,t5=-1.f,t6=-1.f,t7=-1.f,t8=-1.f,t9=-1.f;
  const float4* x4 = reinterpret_cast<const float4*>(x);
  for (int sl = 0; sl < SLPP; ++sl) {
    const size_t base = (size_t)((part * SLPP + sl) * CH + c) * HW4;
    for (int i = tid; i < HW4; i += 256) {
      float4 v = x4[base + i];
      float d0 = fabsf(v.x - mu), d1 = fabsf(v.y - mu);
      float d2 = fabsf(v.z - mu), d3 = fabsf(v.w - mu);
      if (d0 > t0) { t0=d0; CSA(t0,t1);CSA(t1,t2);CSA(t2,t3);CSA(t3,t4);CSA(t4,t5);CSA(t5,t6);CSA(t6,t7);CSA(t7,t8);CSA(t8,t9); }
      if (d1 > t0) { t0=d1; CSA(t0,t1);CSA(t1,t2);CSA(t2,t3);CSA(t3,t4);CSA(t4,t5);CSA(t5,t6);CSA(t6,t7);CSA(t7,t8);CSA(t8,t9); }
      if (d2 > t0) { t0=d2; CSA(t0,t1);CSA(t1,t2);CSA(t2,t3);CSA(t3,t4);CSA(t4,t5);CSA(t5,t6);CSA(t6,t7);CSA(t7,t8);CSA(t8,t9); }
      if (d3 > t0) { t0=d3; CSA(t0,t1);CSA(t1,t2);CSA(t2,t3);CSA(t3,t4);CSA(t4,t5);CSA(t5,t6);CSA(t6,t7);CSA(t7,t8);CSA(t8,t9); }
    }
  }

  __shared__ float shT[KTOP * 256];
  __shared__ float swv[4];
  __shared__ int   swi[4];
  shT[0*256+tid]=t0; shT[1*256+tid]=t1; shT[2*256+tid]=t2; shT[3*256+tid]=t3;
  shT[4*256+tid]=t4; shT[5*256+tid]=t5; shT[6*256+tid]=t6; shT[7*256+tid]=t7;
  shT[8*256+tid]=t8; shT[9*256+tid]=t9;
  __syncthreads();

  const int lane = tid & 63, wid = tid >> 6;
  for (int it = 0; it < KTOP; ++it) {
    float best = -1.f; int bi = 0;
    #pragma unroll
    for (int j = 0; j < KTOP; ++j) {
      float v = shT[j*256 + tid];
      if (v > best) { best = v; bi = j*256 + tid; }
    }
    for (int off = 32; off; off >>= 1) {
      float ov = __shfl_down(best, off);
      int   oi = __shfl_down(bi, off);
      if (ov > best) { best = ov; bi = oi; }
    }
    if (lane == 0) { swv[wid] = best; swi[wid] = bi; }
    __syncthreads();
    if (tid == 0) {
      float bb = swv[0]; int bbi = swi[0];
      for (int w = 1; w < 4; ++w) if (swv[w] > bb) { bb = swv[w]; bbi = swi[w]; }
      tops[bid * KTOP + it] = bb;
      shT[bbi] = -1.f;
    }
    __syncthreads();
  }
}

// ---------------------------------------------------------------------------
// k_finalize: per channel: exact mean; top-10 from candidates (good) or
// from rescued per-part tops (bad); fold (sw, sb).  grid = CH, 256 threads.
// ---------------------------------------------------------------------------
__global__ __launch_bounds__(256) void k_finalize(const float* __restrict__ sums,
                                                  const unsigned* __restrict__ cnt,
                                                  const unsigned* __restrict__ ovf,
                                                  const float* __restrict__ cand,
                                                  const float* __restrict__ tops,
                                                  const float* __restrict__ weight,
                                                  const float* __restrict__ bias,
                                                  float* __restrict__ sw,
                                                  float* __restrict__ sb,
                                                  int cap, float constv) {
  const int c   = blockIdx.x;
  const int tid = threadIdx.x;
  const int lane = tid & 63, wid = tid >> 6;

  // exact mean from 16 partials
  __shared__ float smu;
  float ps = (tid < PARTS) ? sums[tid * CH + c] : 0.f;
  for (int off = 32; off; off >>= 1) ps += __shfl_down(ps, off);
  if (tid == 0) smu = ps * (1.0f / ((float)NBATCH * (float)HWSZ));
  __syncthreads();
  const float mu = smu;

  const unsigned n = cnt[c];
  const bool good = (n >= (unsigned)KTOP) && (n <= (unsigned)cap) &&
                    (n <= (unsigned)SELMAX) && (ovf[c] == 0u);

  __shared__ float ls[SELMAX];
  __shared__ float swv[4];
  __shared__ int   swi[4];
  __shared__ float tot;
  if (tid == 0) tot = 0.f;

  int m;  // number of valid entries in ls
  if (good) {
    m = (int)n;
    const float* cc = cand + (size_t)c * cap;
    for (int i = tid; i < m; i += 256) ls[i] = fabsf(cc[i] - mu);
  } else {
    m = PARTS * KTOP;  // 160 rescued dev values
    for (int i = tid; i < m; i += 256) {
      const int part = i / KTOP, it = i - part * KTOP;
      ls[i] = tops[(part * CH + c) * KTOP + it];
    }
  }
  __syncthreads();

  for (int it = 0; it < KTOP; ++it) {
    float best = -1.f; int bi = 0;
    for (int i = tid; i < m; i += 256) {
      float v = ls[i];
      if (v > best) { best = v; bi = i; }
    }
    for (int off = 32; off; off >>= 1) {
      float ov = __shfl_down(best, off);
      int   oi = __shfl_down(bi, off);
      if (ov > best) { best = ov; bi = oi; }
    }
    if (lane == 0) { swv[wid] = best; swi[wid] = bi; }
    __syncthreads();
    if (tid == 0) {
      float bb = swv[0]; int bbi = swi[0];
      for (int w = 1; w < 4; ++w) if (swv[w] > bb) { bb = swv[w]; bbi = swi[w]; }
      tot += bb;
      ls[bbi] = -1.f;
    }
    __syncthreads();
  }

  if (tid == 0) {
    const float mtk = tot * (1.0f / KTOP) * constv;
    const float inv = 1.f / (mtk + EPSV);
    const float w   = inv * weight[c];
    sw[c] = w;
    sb[c] = bias[c] - mu * w;
  }
}

// ---------------------------------------------------------------------------
// k_affine: out = fma(x, sw[c], sb[c]).  grid = NBATCH*CH, 256 threads
// ---------------------------------------------------------------------------
__global__ __launch_bounds__(256) void k_affine(const float* __restrict__ x,
                                                const float* __restrict__ sw,
                                                const float* __restrict__ sb,
                                                float* __restrict__ out) {
  const int s = blockIdx.x;           // n*CH + c
  const int c = s & (CH - 1);
  const float w = sw[c], b = sb[c];
  const float4* x4 = reinterpret_cast<const float4*>(x) + (size_t)s * HW4;
  float4*       o4 = reinterpret_cast<float4*>(out)     + (size_t)s * HW4;
  for (int i = threadIdx.x; i < HW4; i += 256) {
    float4 v = x4[i];
    float4 r;
    r.x = fmaf(v.x, w, b);
    r.y = fmaf(v.y, w, b);
    r.z = fmaf(v.z, w, b);
    r.w = fmaf(v.w, w, b);
    o4[i] = r;
  }
}

extern "C" void kernel_launch(void* const* d_in, const int* in_sizes, int n_in,
                              void* d_out, int out_size, void* d_ws, size_t ws_size,
                              hipStream_t stream) {
  const float* x      = (const float*)d_in[0];
  const float* weight = (const float*)d_in[1];
  const float* bias   = (const float*)d_in[2];
  float* out = (float*)d_out;
  float* ws  = (float*)d_ws;

  // ws layout (floats)
  float*    sums   = ws;                      // PARTS*CH = 2048
  float*    muhat  = sums + PARTS * CH;       // 128
  float*    taupre = muhat + CH;              // 128
  float*    sw     = taupre + CH;             // 128
  float*    sb     = sw + CH;                 // 128
  float*    tops   = sb + CH;                 // PARTS*CH*KTOP = 20480
  unsigned* cnt    = (unsigned*)(tops + PARTS * CH * KTOP); // 128
  unsigned* ovf    = cnt + CH;                // 128
  float*    cand   = (float*)(ovf + CH);
  const size_t FIXED = (size_t)((float*)cand - ws);

  const size_t avail = ws_size / 4;
  int cap;
  if      (avail >= FIXED + (size_t)CH * 8192) cap = 8192;
  else if (avail >= FIXED + (size_t)CH * 2048) cap = 2048;
  else                                         cap = 1024;

  const double M = (double)NBATCH * (double)HWSZ;
  const float constv =
      (float)(0.5 * (1.0 + sqrt(M_PI * log(4.0))) / sqrt(2.0 * log(M)));

  k_sample<<<CH, 256, 0, stream>>>(x, muhat, taupre, cnt, ovf);
  k_main<<<PARTS * CH, 256, 0, stream>>>(x, muhat, taupre, sums, cnt, ovf, cand, cap);
  k_rescue<<<PARTS * CH, 256, 0, stream>>>(x, sums, cnt, ovf, tops, cap);
  k_finalize<<<CH, 256, 0, stream>>>(sums, cnt, ovf, cand, tops, weight, bias,
                                     sw, sb, cap, constv);
  k_affine<<<NBATCH * CH, 256, 0, stream>>>(x, sw, sb, out);
}